// Round 1
// 2763.550 us; speedup vs baseline: 5.6785x; 5.6785x over previous
//
#include <hip/hip_runtime.h>

#define NGROUP 8
#define NB     32
#define TLEN   2048
#define LLEN   128
#define TDIM   768
#define VDIM   1024
#define ADIM   1024
#define DH     128          // ADIM / NGROUP
#define TT     64           // T tile
#define NTILE  (TLEN / TT)  // 32
#define ESTR   68           // padded stride for E [128][68]
#define CK     64           // K-chunk for phase-A MFMA staging
#define NCHUNK (VDIM / CK)  // 16

// LDS layout (bytes):
//   qT   ushort[128][128]   @0        32768   (qT[dd][l], bf16)
//   vvS  ushort[128][128]   @32768    32768   (vv[l][dim], bf16)
//   kT   ushort[128][64]    @65536    16384   (kT[dim][tt], bf16, row-XOR-swizzled)
//   vtS  ushort[64][128]    @81920    16384   (vt[tt][dim], bf16, linear)
//   E    float[128][68]     @98304    34816   [overlays: Xst f[16][132]=8448 (phase 0);
//                                              WTs ushort[2][128][64]=32768 @98304;
//                                              Vts ushort[64][64]=8192 @131072  (phase A staging)]
//   scale_col f[64]         @139264   256
//   s_row     f[128]        @139520   512
//   bias_k    f[128]        @140032   512
//   bias_vt   f[128]        @140544   512
#define SMEM_BYTES 141056

typedef __bf16 bf16x8 __attribute__((ext_vector_type(8)));
typedef float  f32x4  __attribute__((ext_vector_type(4)));

__device__ __forceinline__ unsigned short f2bf(float f) {
    unsigned int u = __float_as_uint(f);
    u = (u + 0x7fffu + ((u >> 16) & 1u)) >> 16;   // round-to-nearest-even
    return (unsigned short)u;
}
__device__ __forceinline__ float bfbits(unsigned short h) {
    return __uint_as_float(((unsigned int)h) << 16);
}
__device__ __forceinline__ void unpk(unsigned int u, float& lo, float& hi) {
    lo = __uint_as_float(u << 16);
    hi = __uint_as_float(u & 0xffff0000u);
}

// ---- one-time: Wk, Wvt [c=1024][n=1024] fp32 -> workspace W^T [n][c] bf16 ----
extern "C" __global__ void wconv(const float* __restrict__ Wk,
                                 const float* __restrict__ Wvt,
                                 unsigned short* __restrict__ WkT,
                                 unsigned short* __restrict__ WvtT)
{
    __shared__ float tile[2][32][33];
    const int bx = blockIdx.x & 31;      // n-tile
    const int by = blockIdx.x >> 5;      // c-tile
    const int tx = threadIdx.x & 31, ty = threadIdx.x >> 5;   // 32x8
    #pragma unroll
    for (int r = 0; r < 4; ++r) {
        const int c = by * 32 + ty * 4 + r;
        const int n = bx * 32 + tx;
        tile[0][ty * 4 + r][tx] = Wk [(size_t)c * ADIM + n];
        tile[1][ty * 4 + r][tx] = Wvt[(size_t)c * ADIM + n];
    }
    __syncthreads();
    #pragma unroll
    for (int r = 0; r < 4; ++r) {
        const int n = bx * 32 + ty * 4 + r;
        const int c = by * 32 + tx;
        WkT [(size_t)n * VDIM + c] = f2bf(tile[0][tx][ty * 4 + r]);
        WvtT[(size_t)n * VDIM + c] = f2bf(tile[1][tx][ty * 4 + r]);
    }
}

extern "C" __global__ __launch_bounds__(1024)
void attn_fused(const float* __restrict__ videofea,  // [b][vd][T]
                const float* __restrict__ textfea,   // [b][L][td]
                const int*   __restrict__ mask,      // [b][T][L]
                const float* __restrict__ Wq,  const float* __restrict__ bq,
                const float* __restrict__ bk,
                const float* __restrict__ Wvv, const float* __restrict__ bvv,
                const float* __restrict__ bvt,
                const unsigned short* __restrict__ WkTg,   // [ADIM][VDIM] bf16
                const unsigned short* __restrict__ WvtTg,  // [ADIM][VDIM] bf16
                float* __restrict__ out)             // out_v [32][1024][2048] ++ out_t [32][128][1024]
{
    extern __shared__ char smem[];
    unsigned short* qT  = (unsigned short*)(smem);
    unsigned short* vvS = (unsigned short*)(smem + 32768);
    unsigned short* kT  = (unsigned short*)(smem + 65536);
    unsigned short* vtS = (unsigned short*)(smem + 81920);
    float* E    = (float*)(smem + 98304);
    float* Xst  = (float*)(smem + 98304);               // overlay, phase 0 only
    unsigned short* WTs = (unsigned short*)(smem + 98304);   // overlay, phase A staging: [2][128][64]
    unsigned short* Vts = (unsigned short*)(smem + 131072);  // overlay, phase A staging: [64][64]
    float* scale_col = (float*)(smem + 139264);
    float* s_row     = (float*)(smem + 139520);
    float* bias_k    = (float*)(smem + 140032);
    float* bias_vt   = (float*)(smem + 140544);

    const int tid = threadIdx.x;
    const int wid = tid >> 6, lane = tid & 63;
    const int g = blockIdx.x, b = blockIdx.y;
    const int gd0 = g * DH;

    const float* Vb   = videofea + (size_t)b * VDIM * TLEN;
    const float* Xb   = textfea  + (size_t)b * LLEN * TDIM;
    const int*   Mb   = mask     + (size_t)b * TLEN * LLEN;
    float* outv = out;
    float* outt = out + (size_t)NB * ADIM * TLEN;

    // ================= Phase 0: q and vv projections (one-time) =================
    {
        const int tx = tid & 31, ty = tid >> 5;     // dim0 = tx*4, l0 = ty*4
        const int dim0 = tx * 4, l0 = ty * 4;
        float aq[4][4], av[4][4];
        #pragma unroll
        for (int i = 0; i < 4; ++i)
            #pragma unroll
            for (int j = 0; j < 4; ++j) { aq[i][j] = 0.f; av[i][j] = 0.f; }

        for (int c0 = 0; c0 < TDIM; c0 += 16) {
            __syncthreads();  // protect Xst reuse
            #pragma unroll
            for (int r = 0; r < 2; ++r) {
                int idx = r * 1024 + tid;            // 0..2047
                int l = idx >> 4, kk = idx & 15;
                Xst[kk * 132 + l] = Xb[l * TDIM + c0 + kk];
            }
            __syncthreads();
            #pragma unroll 4
            for (int kk = 0; kk < 16; ++kk) {
                const float4 x4 = *(const float4*)&Xst[kk * 132 + l0];
                const float4 wq = *(const float4*)&Wq [(size_t)(c0 + kk) * ADIM + gd0 + dim0];
                const float4 wv = *(const float4*)&Wvv[(size_t)(c0 + kk) * ADIM + gd0 + dim0];
                const float xs[4] = {x4.x, x4.y, x4.z, x4.w};
                const float qs[4] = {wq.x, wq.y, wq.z, wq.w};
                const float vs[4] = {wv.x, wv.y, wv.z, wv.w};
                #pragma unroll
                for (int i = 0; i < 4; ++i)
                    #pragma unroll
                    for (int j = 0; j < 4; ++j) {
                        aq[i][j] += xs[i] * qs[j];
                        av[i][j] += xs[i] * vs[j];
                    }
            }
        }
        const float4 bq4 = *(const float4*)&bq [gd0 + dim0];
        const float4 bv4 = *(const float4*)&bvv[gd0 + dim0];
        const float bqs[4] = {bq4.x, bq4.y, bq4.z, bq4.w};
        const float bvs[4] = {bv4.x, bv4.y, bv4.z, bv4.w};
        #pragma unroll
        for (int j = 0; j < 4; ++j) {   // qT[dim][l]: pack 4 l's
            ushort4 p;
            p.x = f2bf(aq[0][j] + bqs[j]); p.y = f2bf(aq[1][j] + bqs[j]);
            p.z = f2bf(aq[2][j] + bqs[j]); p.w = f2bf(aq[3][j] + bqs[j]);
            *(ushort4*)&qT[(dim0 + j) * LLEN + l0] = p;
        }
        #pragma unroll
        for (int i = 0; i < 4; ++i) {   // vvS[l][dim]: pack 4 dims
            ushort4 p;
            p.x = f2bf(av[i][0] + bvs[0]); p.y = f2bf(av[i][1] + bvs[1]);
            p.z = f2bf(av[i][2] + bvs[2]); p.w = f2bf(av[i][3] + bvs[3]);
            *(ushort4*)&vvS[(l0 + i) * DH + dim0] = p;
        }
    }
    if (tid < 128) {
        s_row[tid]   = 0.f;
        bias_k[tid]  = bk [gd0 + tid];
        bias_vt[tid] = bvt[gd0 + tid];
    }

    // out_t accumulator lives in threads 256..767 (waves 4..11): [l(4)][dim(8)]
    float acct[4][8];
    #pragma unroll
    for (int i = 0; i < 4; ++i)
        #pragma unroll
        for (int j = 0; j < 8; ++j) acct[i][j] = 0.f;
    __syncthreads();

    // ================= main loop over T tiles =================
    for (int it = 0; it < NTILE; ++it) {
        const int t0 = it * TT;

        // ---- Phase A: k/vt projection via bf16 MFMA ----
        // C[tt(64)][dim(128)] = sum_c V[c][t0+tt] * W[c][gd0+dim], W in {Wk, Wvt}
        // waves 0-3 each own a 64x64 output tile: mat = wid>>1, n-half = wid&1
        {
            f32x4 acc[4][4];
            #pragma unroll
            for (int i = 0; i < 4; ++i)
                #pragma unroll
                for (int j = 0; j < 4; ++j)
                    acc[i][j] = (f32x4){0.f, 0.f, 0.f, 0.f};
            const int mat = wid >> 1, nbase = (wid & 1) * 64;  // valid when wid<4
            const int dr = tid >> 3, slot = tid & 7;           // W staging coords

            for (int ch = 0; ch < NCHUNK; ++ch) {
                const int c0 = ch * CK;
                __syncthreads();   // staging buffers free (prev chunk MFMA / prev tile D,E done)
                // V stage: [64 c][64 t] fp32 -> Vts[t][c] bf16, rows XOR-swizzled.
                // wave w loads c-quad w; lane = t. Coalesced 256B global reads.
                {
                    const float* vp = Vb + (size_t)(c0 + wid * 4) * TLEN + t0 + lane;
                    ushort4 p;
                    p.x = f2bf(vp[0]);
                    p.y = f2bf(vp[TLEN]);
                    p.z = f2bf(vp[2 * TLEN]);
                    p.w = f2bf(vp[3 * TLEN]);
                    *(ushort4*)&Vts[lane * CK + ((wid * 4) ^ ((lane & 7) << 3))] = p;
                }
                // W stage: pre-transposed bf16 global (linear read) -> WTs, slot-swizzled write.
                // thread: row dr (0..127), 16B slot; one uint4 per matrix.
                {
                    const size_t gro = ((size_t)(gd0 + dr) << 10) + c0 + (slot << 3);
                    const int lo = dr * CK + ((slot ^ (dr & 7)) << 3);
                    *(uint4*)&WTs[lo]        = *(const uint4*)&WkTg [gro];
                    *(uint4*)&WTs[8192 + lo] = *(const uint4*)&WvtTg[gro];
                }
                __syncthreads();
                if (wid < 4) {
                    #pragma unroll
                    for (int ks = 0; ks < 2; ++ks) {
                        const int kl = ks * 32 + ((lane >> 4) << 3);
                        bf16x8 af[4];
                        #pragma unroll
                        for (int mb = 0; mb < 4; ++mb) {
                            const int ttl = mb * 16 + (lane & 15);
                            af[mb] = *(const bf16x8*)&Vts[ttl * CK + (kl ^ ((ttl & 7) << 3))];
                        }
                        #pragma unroll
                        for (int nb = 0; nb < 4; ++nb) {
                            const int nn = nbase + nb * 16 + (lane & 15);
                            const bf16x8 bfr = *(const bf16x8*)&WTs[mat * 8192 + nn * CK + (kl ^ ((nn & 7) << 3))];
                            #pragma unroll
                            for (int mb = 0; mb < 4; ++mb)
                                acc[mb][nb] = __builtin_amdgcn_mfma_f32_16x16x32_bf16(af[mb], bfr, acc[mb][nb], 0, 0, 0);
                        }
                    }
                }
            }
            // epilogue: +bias, write kT (swizzled [dim][tt]) / vtS (linear [tt][dim])
            if (wid < 4) {
                #pragma unroll
                for (int mb = 0; mb < 4; ++mb) {
                    const int ttb = mb * 16 + ((lane >> 4) << 2);   // C/D row base: (lane>>4)*4
                    #pragma unroll
                    for (int nb = 0; nb < 4; ++nb) {
                        const int dim = nbase + nb * 16 + (lane & 15);  // C/D col: lane&15
                        const f32x4 v = acc[mb][nb];
                        if (mat == 0) {
                            const float bb = bias_k[dim];
                            ushort4 p;
                            p.x = f2bf(v[0] + bb); p.y = f2bf(v[1] + bb);
                            p.z = f2bf(v[2] + bb); p.w = f2bf(v[3] + bb);
                            *(ushort4*)&kT[dim * TT + (ttb ^ ((dim & 7) << 3))] = p;
                        } else {
                            const float bb = bias_vt[dim];
                            #pragma unroll
                            for (int r = 0; r < 4; ++r)
                                vtS[(ttb + r) * DH + dim] = f2bf(v[r] + bb);
                        }
                    }
                }
            }
        }
        __syncthreads();

        // ---- Phase B: S = q·kT, mask, exp -> E (threads 0..511) ----
        if (tid < 512) {
            const int tx = tid & 15, ty = tid >> 4;  // tt0 = tx*4, l0 = ty*4
            const int tt0 = tx * 4, l0 = ty * 4;
            float s[4][4];                           // [l][t]
            #pragma unroll
            for (int i = 0; i < 4; ++i)
                #pragma unroll
                for (int j = 0; j < 4; ++j) s[i][j] = 0.f;

            #pragma unroll 2
            for (int dd = 0; dd < DH; ++dd) {
                ushort4 qr = *(const ushort4*)&qT[dd * LLEN + l0];
                ushort4 kr = *(const ushort4*)&kT[dd * TT + (tt0 ^ ((dd & 7) << 3))];
                float qf[4] = {bfbits(qr.x), bfbits(qr.y), bfbits(qr.z), bfbits(qr.w)};
                float kf[4] = {bfbits(kr.x), bfbits(kr.y), bfbits(kr.z), bfbits(kr.w)};
                #pragma unroll
                for (int i = 0; i < 4; ++i)
                    #pragma unroll
                    for (int j = 0; j < 4; ++j) s[i][j] += qf[i] * kf[j];
            }
            float e[4][4];
            #pragma unroll
            for (int j = 0; j < 4; ++j) {
                const int4 m4 = *(const int4*)&Mb[(size_t)(t0 + tt0 + j) * LLEN + l0];
                const int mm[4] = {m4.x, m4.y, m4.z, m4.w};
                #pragma unroll
                for (int i = 0; i < 4; ++i)
                    e[i][j] = (mm[i] == 0) ? 0.f : __expf(s[i][j]);
            }
            #pragma unroll
            for (int i = 0; i < 4; ++i) {
                float4 e4 = {e[i][0], e[i][1], e[i][2], e[i][3]};
                *(float4*)&E[(l0 + i) * ESTR + tt0] = e4;
            }
        }
        __syncthreads();

        // ---- Phase C: column sums (softmax over L) + row sum accumulation ----
        if (tid < 512) {
            const int col = tid >> 3, sub = tid & 7;
            float cs = 0.f;
            #pragma unroll 4
            for (int l = sub * 16; l < sub * 16 + 16; ++l) cs += E[l * ESTR + col];
            cs += __shfl_xor(cs, 1); cs += __shfl_xor(cs, 2); cs += __shfl_xor(cs, 4);
            if (sub == 0) scale_col[col] = 1.0f / (32.0f * fmaxf(cs, 1e-30f));
        } else {
            const int u = tid - 512;
            const int r = u >> 2, sub = u & 3;
            float rs = 0.f;
            #pragma unroll 4
            for (int tt = sub * 16; tt < sub * 16 + 16; ++tt) rs += E[r * ESTR + tt];
            rs += __shfl_xor(rs, 1); rs += __shfl_xor(rs, 2);
            if (sub == 0) s_row[r] += rs;
        }
        __syncthreads();

        // ---- Phase D (waves 0-3): out_v tile = (E^T · vv) * scale_col
        //      Phase E (waves 4-11): acct += E · vt       (concurrent, read-only LDS)
        if (tid < 256) {
            const int tx = tid & 15, ty = tid >> 4;  // tt0 = tx*4, dim0 = ty*8
            const int tt0 = tx * 4, dim0 = ty * 8;
            float acc[8][4];
            #pragma unroll
            for (int j = 0; j < 8; ++j)
                #pragma unroll
                for (int i = 0; i < 4; ++i) acc[j][i] = 0.f;

            #pragma unroll 2
            for (int l = 0; l < LLEN; ++l) {
                const float4 e4 = *(const float4*)&E[l * ESTR + tt0];
                const float es[4] = {e4.x, e4.y, e4.z, e4.w};
                const uint4 vr = *(const uint4*)&vvS[l * DH + dim0];
                float v8[8];
                unpk(vr.x, v8[0], v8[1]); unpk(vr.y, v8[2], v8[3]);
                unpk(vr.z, v8[4], v8[5]); unpk(vr.w, v8[6], v8[7]);
                #pragma unroll
                for (int j = 0; j < 8; ++j)
                    #pragma unroll
                    for (int i = 0; i < 4; ++i) acc[j][i] += v8[j] * es[i];
            }
            const float4 sc4 = *(const float4*)&scale_col[tt0];
            const float sc[4] = {sc4.x, sc4.y, sc4.z, sc4.w};
            #pragma unroll
            for (int j = 0; j < 8; ++j) {
                float4 o = {acc[j][0] * sc[0], acc[j][1] * sc[1], acc[j][2] * sc[2], acc[j][3] * sc[3]};
                *(float4*)&outv[((size_t)b * ADIM + gd0 + dim0 + j) * TLEN + t0 + tt0] = o;
            }
        } else if (tid < 768) {
            const int u = tid - 256;
            const int tx = u & 15, ty = u >> 4;      // dim0 = tx*8, l0 = ty*4
            const int dim0 = tx * 8, l0 = ty * 4;
            for (int tt4 = 0; tt4 < TT; tt4 += 4) {
                const float4 e0 = *(const float4*)&E[(l0 + 0) * ESTR + tt4];
                const float4 e1 = *(const float4*)&E[(l0 + 1) * ESTR + tt4];
                const float4 e2 = *(const float4*)&E[(l0 + 2) * ESTR + tt4];
                const float4 e3 = *(const float4*)&E[(l0 + 3) * ESTR + tt4];
                const float er[4][4] = {{e0.x, e0.y, e0.z, e0.w}, {e1.x, e1.y, e1.z, e1.w},
                                        {e2.x, e2.y, e2.z, e2.w}, {e3.x, e3.y, e3.z, e3.w}};
                #pragma unroll
                for (int s = 0; s < 4; ++s) {
                    const uint4 vr = *(const uint4*)&vtS[(tt4 + s) * DH + dim0];
                    float v8[8];
                    unpk(vr.x, v8[0], v8[1]); unpk(vr.y, v8[2], v8[3]);
                    unpk(vr.z, v8[4], v8[5]); unpk(vr.w, v8[6], v8[7]);
                    #pragma unroll
                    for (int i = 0; i < 4; ++i)
                        #pragma unroll
                        for (int j = 0; j < 8; ++j) acct[i][j] += er[i][s] * v8[j];
                }
            }
        }
        __syncthreads();  // protect kT/vtS/E/staging before next tile's Phase A
    }

    // ================= epilogue: out_t = acct / (32 * s_row) =================
    if (tid >= 256 && tid < 768) {
        const int u = tid - 256;
        const int tx = u & 15, ty = u >> 4;
        const int dim0 = tx * 8, l0 = ty * 4;
        #pragma unroll
        for (int i = 0; i < 4; ++i) {
            float inv = 1.0f / (32.0f * fmaxf(s_row[l0 + i], 1e-30f));
            float4 o0 = {acct[i][0] * inv, acct[i][1] * inv, acct[i][2] * inv, acct[i][3] * inv};
            float4 o1 = {acct[i][4] * inv, acct[i][5] * inv, acct[i][6] * inv, acct[i][7] * inv};
            size_t base = (size_t)b * LLEN * ADIM + (size_t)(l0 + i) * ADIM + gd0 + dim0;
            *(float4*)&outt[base]     = o0;
            *(float4*)&outt[base + 4] = o1;
        }
    }
}

extern "C" void kernel_launch(void* const* d_in, const int* in_sizes, int n_in,
                              void* d_out, int out_size, void* d_ws, size_t ws_size,
                              hipStream_t stream) {
    const float* videofea = (const float*)d_in[0];
    const float* textfea  = (const float*)d_in[1];
    const int*   mask     = (const int*)d_in[2];
    const float* Wq  = (const float*)d_in[3];
    const float* bq  = (const float*)d_in[4];
    const float* Wk  = (const float*)d_in[5];
    const float* bk  = (const float*)d_in[6];
    const float* Wvv = (const float*)d_in[7];
    const float* bvv = (const float*)d_in[8];
    const float* Wvt = (const float*)d_in[9];
    const float* bvt = (const float*)d_in[10];
    float* out = (float*)d_out;

    // workspace: WkT bf16 [1024][1024] ++ WvtT bf16 [1024][1024] = 4 MB
    unsigned short* WkTg  = (unsigned short*)d_ws;
    unsigned short* WvtTg = WkTg + (size_t)ADIM * VDIM;

    wconv<<<dim3(1024), dim3(256), 0, stream>>>(Wk, Wvt, WkTg, WvtTg);

    hipFuncSetAttribute((const void*)attn_fused,
                        hipFuncAttributeMaxDynamicSharedMemorySize, SMEM_BYTES);
    dim3 grid(NGROUP, NB);
    attn_fused<<<grid, 1024, SMEM_BYTES, stream>>>(
        videofea, textfea, mask, Wq, bq, bk, Wvv, bvv, bvt, WkTg, WvtTg, out);
}